// Round 4
// baseline (461.763 us; speedup 1.0000x reference)
//
#include <hip/hip_runtime.h>
#include <math.h>

#define N_ROWS 65536
#define D 256
#define K 2048

// d_out float layout: z_q_st | loss | indices | perplexity
#define LOSS_OFF 16777216L
#define IDX_OFF  16777217L
#define PERP_OFF 16842753L

// ws byte layout
#define WS_HIST    0           // 2048*4
#define WS_LOSS    8192
#define WS_FLAGCNT 8196
#define WS_ENORM   8448        // 2048*4
#define WS_ZNORM   16640       // 65536*4
#define WS_FLAGS   278784      // 65536*4
#define WS_BPK     540928      // 1 MB  [stage(nt*8+kc)][code][quad-perm] fp16

#define MARGIN 0.125f

typedef _Float16 half8 __attribute__((ext_vector_type(8)));
typedef float floatx4 __attribute__((ext_vector_type(4)));

__device__ __forceinline__ void gload16(const void* g, void* l) {
  __builtin_amdgcn_global_load_lds((const __attribute__((address_space(1))) void*)g,
                                   (__attribute__((address_space(3))) void*)l, 16, 0, 0);
}

// ---- convert A: z fp32 -> fp16 packed apk[row][kc^(row&1)][quad^((row>>1)&3)] + znorm
__global__ __launch_bounds__(256) void convertA_kernel(const float* __restrict__ z,
                                                       char* __restrict__ apk,
                                                       float* __restrict__ znorm) {
  const int gid = blockIdx.x * 256 + threadIdx.x;   // 524288
  const int row = gid >> 3, c = gid & 7;
  const float4* s4 = (const float4*)(z + (size_t)row * D + c * 32);
  float buf[32];
#pragma unroll
  for (int q = 0; q < 8; ++q) *(float4*)&buf[q * 4] = s4[q];
  float s = 0.f;
#pragma unroll
  for (int k = 0; k < 32; ++k) s = fmaf(buf[k], buf[k], s);
  s += __shfl_xor(s, 1, 64); s += __shfl_xor(s, 2, 64); s += __shfl_xor(s, 4, 64);
  if ((threadIdx.x & 7) == 0) znorm[row] = s;
  _Float16 hi[32];
#pragma unroll
  for (int k = 0; k < 32; ++k) hi[k] = (_Float16)buf[k];
  char* dst = apk + (size_t)row * 512 + ((c ^ (row & 1)) * 64);
  const int qp = (row >> 1) & 3;
#pragma unroll
  for (int q = 0; q < 4; ++q)
    *(uint4*)(dst + ((q ^ qp) * 16)) = ((const uint4*)hi)[q];
}

// ---- convert B: ew fp32 -> fp16 bpk[stage][code][quad-perm] + enorm (exact fp32)
__global__ __launch_bounds__(256) void convertB_kernel(const float* __restrict__ ew,
                                                       char* __restrict__ bpk,
                                                       float* __restrict__ enorm) {
  const int gid = blockIdx.x * 256 + threadIdx.x;   // 16384
  const int code = gid >> 3, c = gid & 7;           // c = kc
  const float4* s4 = (const float4*)(ew + (size_t)code * D + c * 32);
  float buf[32];
#pragma unroll
  for (int q = 0; q < 8; ++q) *(float4*)&buf[q * 4] = s4[q];
  float s = 0.f;
#pragma unroll
  for (int k = 0; k < 32; ++k) s = fmaf(buf[k], buf[k], s);
  s += __shfl_xor(s, 1, 64); s += __shfl_xor(s, 2, 64); s += __shfl_xor(s, 4, 64);
  if ((threadIdx.x & 7) == 0) enorm[code] = s;
  _Float16 hi[32];
#pragma unroll
  for (int k = 0; k < 32; ++k) hi[k] = (_Float16)buf[k];
  const int nt = code >> 7, cl = code & 127;
  const int stage = nt * 8 + c;
  char* dst = bpk + (size_t)stage * 8192 + cl * 64;
  const int qp = (cl >> 1) & 3;
#pragma unroll
  for (int q = 0; q < 4; ++q)
    *(uint4*)(dst + ((q ^ qp) * 16)) = ((const uint4*)hi)[q];
}

// ---- MFMA distance GEMM: A-tile resident in LDS, B double-buffered, fused argmin+loss
__global__ __launch_bounds__(256, 2) void argmin_mfma_kernel(
    const char* __restrict__ apk, const char* __restrict__ bpk,
    const float* __restrict__ enorm, const float* __restrict__ znorm,
    float* __restrict__ out_idx, float* __restrict__ loss_acc,
    int* __restrict__ flagcnt, int* __restrict__ flags) {
  __shared__ __align__(16) char As[65536];      // 128 rows x 512B (swizzled)
  __shared__ __align__(16) char Bs[2][8192];    // double-buffered (nt,kc) chunk

  const int t = threadIdx.x, lane = t & 63, w = t >> 6;
  const int quad = lane >> 4, l15 = lane & 15;
  const int wrow = w * 32;
  const size_t rowbase = (size_t)blockIdx.x * 128;

  // stage A-tile: 64 KB contiguous from apk
#pragma unroll
  for (int site = 0; site < 16; ++site)
    gload16(apk + rowbase * 512 + site * 4096 + t * 16, As + site * 4096 + t * 16);
  // stage B chunk 0
  gload16(bpk + t * 16, Bs[0] + t * 16);
  gload16(bpk + 4096 + t * 16, Bs[0] + 4096 + t * 16);

  // swizzled read offsets
  const int perm16 = ((quad ^ ((l15 >> 1) & 3)) * 16);
  const int kx64   = (l15 & 1) * 64;
  const int abase  = (wrow + l15) * 512 + perm16;   // + rt*8192 + ((kc*64)^kx64)
  const int bbase  = l15 * 64 + perm16;             // + ct*1024 (+ buf*8192)

  float best[8], sec[8]; int bidx[8];
#pragma unroll
  for (int s = 0; s < 8; ++s) { best[s] = 3.0e38f; sec[s] = 3.0e38f; bidx[s] = 0; }
  float lsum = 0.f;

  __syncthreads();

#pragma unroll 1
  for (int nt = 0; nt < 16; ++nt) {
    floatx4 acc[2][8];
#pragma unroll
    for (int rt = 0; rt < 2; ++rt)
#pragma unroll
      for (int ct = 0; ct < 8; ++ct) acc[rt][ct] = 0;

#pragma unroll
    for (int kc = 0; kc < 8; ++kc) {
      const int s = nt * 8 + kc, ns = s + 1;
      if (ns < 128) {
        const char* src = bpk + (size_t)ns * 8192 + t * 16;
        char* dst = Bs[ns & 1] + t * 16;
        gload16(src, dst);
        gload16(src + 4096, dst + 4096);
      }
      const char* bb = Bs[s & 1];
      const int ao = abase + ((kc * 64) ^ kx64);
      const half8 av0 = *(const half8*)(As + ao);
      const half8 av1 = *(const half8*)(As + ao + 8192);
#pragma unroll
      for (int ct = 0; ct < 8; ++ct) {
        const half8 bv = *(const half8*)(bb + ct * 1024 + bbase);
        acc[0][ct] = __builtin_amdgcn_mfma_f32_16x16x32_f16(av0, bv, acc[0][ct], 0, 0, 0);
        acc[1][ct] = __builtin_amdgcn_mfma_f32_16x16x32_f16(av1, bv, acc[1][ct], 0, 0, 0);
      }
      __syncthreads();
    }

    // epilogue: dist = ||e||^2 - 2 z.e
#pragma unroll
    for (int ct = 0; ct < 8; ++ct) {
      const int cg = nt * 128 + ct * 16 + l15;
      const float en = enorm[cg];
#pragma unroll
      for (int rt = 0; rt < 2; ++rt)
#pragma unroll
        for (int r = 0; r < 4; ++r) {
          const float dv = fmaf(-2.0f, acc[rt][ct][r], en);
          const int s = rt * 4 + r;
          if (dv < best[s]) { sec[s] = best[s]; best[s] = dv; bidx[s] = cg; }
          else if (dv < sec[s]) sec[s] = dv;
        }
    }
  }

  // merge across the 16 lanes holding each row + loss + margin flags
#pragma unroll
  for (int s = 0; s < 8; ++s) {
    float b = best[s], s2 = sec[s];
    int bi = bidx[s];
#pragma unroll
    for (int m = 1; m < 16; m <<= 1) {
      const float ob = __shfl_xor(b, m, 64);
      const float os = __shfl_xor(s2, m, 64);
      const int   oi = __shfl_xor(bi, m, 64);
      const bool take = (ob < b) || (ob == b && oi < bi);
      const float loser = take ? b : ob;
      if (take) { b = ob; bi = oi; }
      s2 = fminf(fminf(s2, os), loser);
    }
    if (l15 == 0) {
      const int rowg = (int)rowbase + wrow + (s >> 2) * 16 + quad * 4 + (s & 3);
      out_idx[rowg] = (float)bi;
      lsum += b + znorm[rowg];
      if (s2 - b < MARGIN) {
        const int p = atomicAdd(flagcnt, 1);
        flags[p] = rowg;
      }
    }
  }
  lsum += __shfl_down(lsum, 16, 64);
  lsum += __shfl_down(lsum, 32, 64);
  if (lane == 0) atomicAdd(loss_acc, lsum);
}

// ---- exact fp32 rescue for near-tie rows (indices only)
__global__ __launch_bounds__(256) void rescue_kernel(const float* __restrict__ z,
                                                     const float* __restrict__ ew,
                                                     const float* __restrict__ enorm,
                                                     const int* __restrict__ flagcnt,
                                                     const int* __restrict__ flags,
                                                     float* __restrict__ out_idx) {
  __shared__ __align__(16) float zs[8][256];
  __shared__ unsigned long long bkey[8];
  const int t = threadIdx.x;
  const int cnt = flagcnt[0];
  for (int grp = blockIdx.x; grp * 8 < cnt; grp += gridDim.x) {
    const int nr = min(8, cnt - grp * 8);
    __syncthreads();
    {
      const int rr = t >> 5, d8 = t & 31;
      if (rr < nr) {
        const int row = flags[grp * 8 + rr];
        const float4* s = (const float4*)(z + (size_t)row * D + d8 * 8);
        *(float4*)&zs[rr][d8 * 8]     = s[0];
        *(float4*)&zs[rr][d8 * 8 + 4] = s[1];
      }
    }
    if (t < 8) bkey[t] = ~0ULL;
    __syncthreads();

    unsigned long long mykey[8];
#pragma unroll
    for (int rr = 0; rr < 8; ++rr) mykey[rr] = ~0ULL;

    for (int cc = 0; cc < 8; ++cc) {
      const int c = cc * 256 + t;
      float acc[8];
#pragma unroll
      for (int rr = 0; rr < 8; ++rr) acc[rr] = 0.f;
      const float4* ev = (const float4*)(ew + (size_t)c * D);
#pragma unroll 2
      for (int d4 = 0; d4 < 64; ++d4) {
        const float4 e = ev[d4];
#pragma unroll
        for (int rr = 0; rr < 8; ++rr) {
          const float4 zz = *(const float4*)&zs[rr][d4 * 4];
          float a = acc[rr];
          a = fmaf(e.x, zz.x, a); a = fmaf(e.y, zz.y, a);
          a = fmaf(e.z, zz.z, a); a = fmaf(e.w, zz.w, a);
          acc[rr] = a;
        }
      }
      const float en = enorm[c];
#pragma unroll
      for (int rr = 0; rr < 8; ++rr) {
        const float dv = fmaf(-2.0f, acc[rr], en);
        const unsigned b = __float_as_uint(dv);
        const unsigned k32 = b ^ ((unsigned)((int)b >> 31) | 0x80000000u);
        const unsigned long long key = ((unsigned long long)k32 << 32) | (unsigned)c;
        if (key < mykey[rr]) mykey[rr] = key;
      }
    }
#pragma unroll
    for (int rr = 0; rr < 8; ++rr)
      if (rr < nr) atomicMin(&bkey[rr], mykey[rr]);
    __syncthreads();
    if (t < nr) out_idx[flags[grp * 8 + t]] = (float)(unsigned)(bkey[t] & 0xFFFFFFFFu);
  }
}

// ---- gather: z_q_st value == ew[idx]; also histogram (post-rescue)
__global__ __launch_bounds__(256) void gather_kernel(const float* __restrict__ ew,
                                                     const float* __restrict__ out_idx,
                                                     float* __restrict__ out,
                                                     int* __restrict__ hist) {
  const size_t NV = (size_t)N_ROWS * (D / 4);
  size_t v = (size_t)blockIdx.x * 256 + threadIdx.x;
  const size_t stride = (size_t)gridDim.x * 256;
  for (; v < NV; v += stride) {
    const size_t row = v >> 6;
    const int d4 = (int)(v & 63);
    const int idx = (int)out_idx[row];
    if (d4 == 0) atomicAdd(&hist[idx], 1);
    ((float4*)out)[v] = ((const float4*)ew)[(size_t)idx * 64 + d4];
  }
}

// ---- loss + perplexity
__global__ __launch_bounds__(256) void finalize_kernel(const int* __restrict__ hist,
                                                       const float* __restrict__ loss_acc,
                                                       float* __restrict__ out) {
  __shared__ float red[256];
  const int t = threadIdx.x;
  float local = 0.f;
  for (int k = t; k < K; k += 256) {
    const float p = (float)hist[k] * (1.0f / (float)N_ROWS);
    local += p * logf(p + 1e-10f);
  }
  red[t] = local;
  __syncthreads();
  for (int s = 128; s > 0; s >>= 1) {
    if (t < s) red[t] += red[t + s];
    __syncthreads();
  }
  if (t == 0) {
    out[LOSS_OFF] = 0.25f * loss_acc[0] * (1.0f / (float)((size_t)N_ROWS * D));
    out[PERP_OFF] = expf(-red[0]);
  }
}

extern "C" void kernel_launch(void* const* d_in, const int* in_sizes, int n_in,
                              void* d_out, int out_size, void* d_ws, size_t ws_size,
                              hipStream_t stream) {
  const float* z  = (const float*)d_in[0];
  const float* ew = (const float*)d_in[1];
  float* out = (float*)d_out;

  char* ws = (char*)d_ws;
  int*   hist     = (int*)(ws + WS_HIST);
  float* loss_acc = (float*)(ws + WS_LOSS);
  int*   flagcnt  = (int*)(ws + WS_FLAGCNT);
  float* enorm    = (float*)(ws + WS_ENORM);
  float* znorm    = (float*)(ws + WS_ZNORM);
  int*   flags    = (int*)(ws + WS_FLAGS);
  char*  bpk      = ws + WS_BPK;
  char*  apk      = (char*)d_out;          // 32 MB scratch in z_q region (overwritten by gather)

  hipMemsetAsync(d_ws, 0, 8448, stream);   // hist + loss + flagcnt

  convertA_kernel<<<2048, 256, 0, stream>>>(z, apk, znorm);
  convertB_kernel<<<64, 256, 0, stream>>>(ew, bpk, enorm);
  argmin_mfma_kernel<<<N_ROWS / 128, 256, 0, stream>>>(apk, bpk, enorm, znorm,
                                                       out + IDX_OFF, loss_acc,
                                                       flagcnt, flags);
  rescue_kernel<<<512, 256, 0, stream>>>(z, ew, enorm, flagcnt, flags, out + IDX_OFF);
  gather_kernel<<<2048, 256, 0, stream>>>(ew, out + IDX_OFF, out, hist);
  finalize_kernel<<<1, 256, 0, stream>>>(hist, loss_acc, out);
}

// Round 5
// 412.663 us; speedup vs baseline: 1.1190x; 1.1190x over previous
//
#include <hip/hip_runtime.h>
#include <math.h>

#define N_ROWS 65536
#define D 256
#define K 2048

// d_out float layout: z_q_st | loss | indices | perplexity
#define LOSS_OFF 16777216L
#define IDX_OFF  16777217L
#define PERP_OFF 16842753L

// ws byte layout
#define WS_HIST    0           // 2048*4
#define WS_LOSS    8192
#define WS_FLAGCNT 8196
#define WS_ENORM   8448        // 2048*4 (exact fp32, rescue)
#define WS_ENORM64 16640       // 2048*4 (64*enorm, argmin epilogue)
#define WS_FLAGS   24832       // 65536*4
#define WS_BPK     287232      // 1 MB frag-packed B

#define FLAG_Q 12              // quantized-gap threshold (12/64 = 0.1875)

typedef _Float16 half8 __attribute__((ext_vector_type(8)));
typedef float floatx4 __attribute__((ext_vector_type(4)));

// ---- convert B: ew fp32 -> fp16 frag-packed bpk + enorm/enorm64 + zero accumulators
__global__ __launch_bounds__(256) void convertB_kernel(const float* __restrict__ ew,
                                                       char* __restrict__ bpk,
                                                       float* __restrict__ enorm,
                                                       float* __restrict__ enorm64,
                                                       int* __restrict__ hist,
                                                       float* __restrict__ loss_acc,
                                                       int* __restrict__ flagcnt) {
  const int gid = blockIdx.x * 256 + threadIdx.x;   // 16384
  if (gid < 2048) hist[gid] = 0;
  else if (gid == 2048) *loss_acc = 0.f;
  else if (gid == 2049) *flagcnt = 0;

  const int code = gid >> 3, kc = gid & 7;
  const float4* s4 = (const float4*)(ew + (size_t)code * D + kc * 32);
  float buf[32];
#pragma unroll
  for (int q = 0; q < 8; ++q) *(float4*)&buf[q * 4] = s4[q];
  float s = 0.f;
#pragma unroll
  for (int k = 0; k < 32; ++k) s = fmaf(buf[k], buf[k], s);
  s += __shfl_xor(s, 1, 64); s += __shfl_xor(s, 2, 64); s += __shfl_xor(s, 4, 64);
  if (kc == 0) { enorm[code] = s; enorm64[code] = s * 64.0f; }
  _Float16 hi[32];
#pragma unroll
  for (int k = 0; k < 32; ++k) hi[k] = (_Float16)buf[k];
  // chunk = (code>>4)*8 + kc ; within chunk lane = (code&15) + 16*q holds halfs q*8..q*8+7
  char* base = bpk + (((size_t)(code >> 4) * 8 + kc) << 10) + (code & 15) * 16;
#pragma unroll
  for (int q = 0; q < 4; ++q)
    *(uint4*)(base + q * 256) = ((const uint4*)hi)[q];
}

// ---- fused: A-convert+stage, barrier-free MFMA argmin, loss, hist, z_q gather
__global__ __launch_bounds__(256, 2) void argmin_kernel(
    const float* __restrict__ z, const float* __restrict__ ew,
    const char* __restrict__ bpk, const float* __restrict__ enorm64,
    float* __restrict__ out, float* __restrict__ out_idx,
    float* __restrict__ loss_acc, int* __restrict__ hist,
    int* __restrict__ flagcnt, int* __restrict__ flags) {
  __shared__ __align__(16) char As[65536];   // [chunk(rg*8+kc)][lane] fp16 frags
  __shared__ float red[4];

  const int t = threadIdx.x, lane = t & 63, w = t >> 6;
  const int quad = lane >> 4, l15 = lane & 15;
  const int h = w & 1, cq = w >> 1;          // row-half, col-half of wave
  const int rb = blockIdx.x * 128;

  // ---- stage A: fp32 -> fp16 frag layout in LDS; fused ||z||^2 partial
  float zsum = 0.f;
#pragma unroll
  for (int i = 0; i < 16; ++i) {
    const int slot = i * 256 + t;
    const int chunk = slot >> 6, ln = slot & 63;
    const int rg = chunk >> 3, kc = chunk & 7;
    const int row = rb + rg * 16 + (ln & 15);
    const float* src = z + (size_t)row * D + kc * 32 + (ln >> 4) * 8;
    const float4 f0 = *(const float4*)src;
    const float4 f1 = *(const float4*)(src + 4);
    zsum += f0.x*f0.x + f0.y*f0.y + f0.z*f0.z + f0.w*f0.w
          + f1.x*f1.x + f1.y*f1.y + f1.z*f1.z + f1.w*f1.w;
    _Float16 hb[8] = {(_Float16)f0.x, (_Float16)f0.y, (_Float16)f0.z, (_Float16)f0.w,
                      (_Float16)f1.x, (_Float16)f1.y, (_Float16)f1.z, (_Float16)f1.w};
    *(uint4*)(As + slot * 16) = *(const uint4*)hb;
  }
  __syncthreads();

  int min1[16], min2[16];
#pragma unroll
  for (int s = 0; s < 16; ++s) { min1[s] = 0x7FFFFFFF; min2[s] = 0x7FFFFFFF; }

  // ---- main loop: ZERO barriers (A read-only in LDS, B streamed from L2)
#pragma unroll 1
  for (int nt = 0; nt < 8; ++nt) {
    floatx4 acc[4][8];
#pragma unroll
    for (int rt = 0; rt < 4; ++rt)
#pragma unroll
      for (int ct = 0; ct < 8; ++ct) acc[rt][ct] = 0;

    const char* bnt = bpk + (((size_t)(nt * 16 + cq * 8) * 8) << 10) + lane * 16;
#pragma unroll 1
    for (int kc = 0; kc < 8; ++kc) {
      half8 a[4], b[8];
#pragma unroll
      for (int rt = 0; rt < 4; ++rt)
        a[rt] = *(const half8*)(As + (((h * 4 + rt) * 8 + kc) << 10) + lane * 16);
#pragma unroll
      for (int ct = 0; ct < 8; ++ct)
        b[ct] = *(const half8*)(bnt + ct * 8192 + (kc << 10));
#pragma unroll
      for (int rt = 0; rt < 4; ++rt)
#pragma unroll
        for (int ct = 0; ct < 8; ++ct)
          acc[rt][ct] = __builtin_amdgcn_mfma_f32_16x16x32_f16(a[rt], b[ct], acc[rt][ct], 0, 0, 0);
    }

    // epilogue: quantized integer keys, min1/min2 per row-slot
#pragma unroll
    for (int ct = 0; ct < 8; ++ct) {
      const int cg = nt * 256 + cq * 128 + ct * 16 + l15;
      const float en = enorm64[cg];
#pragma unroll
      for (int rt = 0; rt < 4; ++rt)
#pragma unroll
        for (int r = 0; r < 4; ++r) {
          const int q = (int)fmaf(-128.0f, acc[rt][ct][r], en);  // trunc(64*dist)
          const int key = q * 2048 + cg;
          const int s = rt * 4 + r;
          min2[s] = min(min2[s], max(key, min1[s]));
          min1[s] = min(min1[s], key);
        }
    }
  }

  // ---- merge: 16 lanes of same row, then across the cq wave pair via LDS
#pragma unroll
  for (int s = 0; s < 16; ++s) {
    int m1 = min1[s], m2 = min2[s];
#pragma unroll
    for (int m = 1; m < 16; m <<= 1) {
      const int o1 = __shfl_xor(m1, m, 64);
      const int o2 = __shfl_xor(m2, m, 64);
      m2 = min(min(m2, o2), max(m1, o1));
      m1 = min(m1, o1);
    }
    min1[s] = m1; min2[s] = m2;
  }
  __syncthreads();                       // As now reusable as scratch
  int* lm1 = (int*)As;                   // [cq][128]
  int* lm2 = lm1 + 256;
  int* lidx = lm2 + 256;                 // [128]
#pragma unroll
  for (int s = 0; s < 16; ++s) {
    if (l15 == 0) {
      const int rowl = h * 64 + (s >> 2) * 16 + quad * 4 + (s & 3);
      lm1[cq * 128 + rowl] = min1[s];
      lm2[cq * 128 + rowl] = min2[s];
    }
  }
  __syncthreads();

  int qbest = 0;
  if (t < 128) {
    const int a1 = lm1[t], b1 = lm1[128 + t];
    const int a2 = lm2[t], b2 = lm2[128 + t];
    const int m1 = min(a1, b1);
    const int m2 = min(min(a2, b2), max(a1, b1));
    const int idxv = m1 & 2047;
    out_idx[rb + t] = (float)idxv;
    lidx[t] = idxv;
    qbest = (m1 >> 11);
    atomicAdd(&hist[idxv], 1);
    if ((m2 >> 11) - (m1 >> 11) < FLAG_Q) {
      const int p = atomicAdd(flagcnt, 1);
      flags[p] = rb + t;
    }
  }
  __syncthreads();

  // ---- z_q write: row value == ew[idx] (L2-hot broadcast)
  {
    const int rr = t >> 1, half = (t & 1) * 32;   // 32 float4 per half-row
    const int idx = lidx[rr];
    const float4* src = (const float4*)(ew + (size_t)idx * D) + half;
    float4* dst = (float4*)(out + ((size_t)rb + rr) * D) + half;
#pragma unroll
    for (int i = 0; i < 32; ++i) dst[i] = src[i];
  }

  // ---- loss: sum(best_dist) + sum(||z||^2), block-reduced
  float lv = zsum + (float)qbest * (1.0f / 64.0f);
#pragma unroll
  for (int off = 32; off > 0; off >>= 1) lv += __shfl_down(lv, off, 64);
  if (lane == 0) red[w] = lv;
  __syncthreads();
  if (t == 0) atomicAdd(loss_acc, red[0] + red[1] + red[2] + red[3]);
}

// ---- exact fp32 rescue: fix idx, hist, z_q for near-tie rows
__global__ __launch_bounds__(256) void rescue_kernel(const float* __restrict__ z,
                                                     const float* __restrict__ ew,
                                                     const float* __restrict__ enorm,
                                                     const int* __restrict__ flagcnt,
                                                     const int* __restrict__ flags,
                                                     float* __restrict__ out_idx,
                                                     float* __restrict__ out,
                                                     int* __restrict__ hist) {
  __shared__ __align__(16) float zs[8][256];
  __shared__ unsigned long long bkey[8];
  __shared__ int rrow[8], ridx[8], rchg[8];
  const int t = threadIdx.x;
  const int cnt = flagcnt[0];
  for (int grp = blockIdx.x; grp * 8 < cnt; grp += gridDim.x) {
    const int nr = min(8, cnt - grp * 8);
    __syncthreads();
    {
      const int rr = t >> 5, d8 = t & 31;
      if (rr < nr) {
        const int row = flags[grp * 8 + rr];
        if (d8 == 0) rrow[rr] = row;
        const float4* s = (const float4*)(z + (size_t)row * D + d8 * 8);
        *(float4*)&zs[rr][d8 * 8]     = s[0];
        *(float4*)&zs[rr][d8 * 8 + 4] = s[1];
      }
    }
    if (t < 8) bkey[t] = ~0ULL;
    __syncthreads();

    unsigned long long mykey[8];
#pragma unroll
    for (int rr = 0; rr < 8; ++rr) mykey[rr] = ~0ULL;

    for (int cc = 0; cc < 8; ++cc) {
      const int c = cc * 256 + t;
      float acc[8];
#pragma unroll
      for (int rr = 0; rr < 8; ++rr) acc[rr] = 0.f;
      const float4* ev = (const float4*)(ew + (size_t)c * D);
#pragma unroll 2
      for (int d4 = 0; d4 < 64; ++d4) {
        const float4 e = ev[d4];
#pragma unroll
        for (int rr = 0; rr < 8; ++rr) {
          const float4 zz = *(const float4*)&zs[rr][d4 * 4];
          float a = acc[rr];
          a = fmaf(e.x, zz.x, a); a = fmaf(e.y, zz.y, a);
          a = fmaf(e.z, zz.z, a); a = fmaf(e.w, zz.w, a);
          acc[rr] = a;
        }
      }
      const float en = enorm[c];
#pragma unroll
      for (int rr = 0; rr < 8; ++rr) {
        const float dv = fmaf(-2.0f, acc[rr], en);
        const unsigned b = __float_as_uint(dv);
        const unsigned k32 = b ^ ((unsigned)((int)b >> 31) | 0x80000000u);
        const unsigned long long key = ((unsigned long long)k32 << 32) | (unsigned)c;
        if (key < mykey[rr]) mykey[rr] = key;
      }
    }
#pragma unroll
    for (int rr = 0; rr < 8; ++rr)
      if (rr < nr) atomicMin(&bkey[rr], mykey[rr]);
    __syncthreads();
    if (t < nr) {
      const int row = rrow[t];
      const int newidx = (int)(unsigned)(bkey[t] & 0xFFFFFFFFu);
      const int oldidx = (int)out_idx[row];
      ridx[t] = newidx;
      rchg[t] = (newidx != oldidx);
      if (newidx != oldidx) {
        atomicSub(&hist[oldidx], 1);
        atomicAdd(&hist[newidx], 1);
        out_idx[row] = (float)newidx;
      }
    }
    __syncthreads();
    {
      const int rr = t >> 5, c8 = (t & 31) * 2;
      if (rr < nr && rchg[rr]) {
        const int row = rrow[rr], idx = ridx[rr];
        const float4* src = (const float4*)(ew + (size_t)idx * D) + c8;
        float4* dst = (float4*)(out + (size_t)row * D) + c8;
        dst[0] = src[0]; dst[1] = src[1];
      }
    }
  }
}

// ---- loss + perplexity
__global__ __launch_bounds__(256) void finalize_kernel(const int* __restrict__ hist,
                                                       const float* __restrict__ loss_acc,
                                                       float* __restrict__ out) {
  __shared__ float red[256];
  const int t = threadIdx.x;
  float local = 0.f;
  for (int k = t; k < K; k += 256) {
    const float p = (float)hist[k] * (1.0f / (float)N_ROWS);
    local += p * logf(p + 1e-10f);
  }
  red[t] = local;
  __syncthreads();
  for (int s = 128; s > 0; s >>= 1) {
    if (t < s) red[t] += red[t + s];
    __syncthreads();
  }
  if (t == 0) {
    out[LOSS_OFF] = 0.25f * loss_acc[0] * (1.0f / (float)((size_t)N_ROWS * D));
    out[PERP_OFF] = expf(-red[0]);
  }
}

extern "C" void kernel_launch(void* const* d_in, const int* in_sizes, int n_in,
                              void* d_out, int out_size, void* d_ws, size_t ws_size,
                              hipStream_t stream) {
  const float* z  = (const float*)d_in[0];
  const float* ew = (const float*)d_in[1];
  float* out = (float*)d_out;

  char* ws = (char*)d_ws;
  int*   hist     = (int*)(ws + WS_HIST);
  float* loss_acc = (float*)(ws + WS_LOSS);
  int*   flagcnt  = (int*)(ws + WS_FLAGCNT);
  float* enorm    = (float*)(ws + WS_ENORM);
  float* enorm64  = (float*)(ws + WS_ENORM64);
  int*   flags    = (int*)(ws + WS_FLAGS);
  char*  bpk      = ws + WS_BPK;

  convertB_kernel<<<64, 256, 0, stream>>>(ew, bpk, enorm, enorm64,
                                          hist, loss_acc, flagcnt);
  argmin_kernel<<<N_ROWS / 128, 256, 0, stream>>>(z, ew, bpk, enorm64,
                                                  out, out + IDX_OFF, loss_acc,
                                                  hist, flagcnt, flags);
  rescue_kernel<<<512, 256, 0, stream>>>(z, ew, enorm, flagcnt, flags,
                                         out + IDX_OFF, out, hist);
  finalize_kernel<<<1, 256, 0, stream>>>(hist, loss_acc, out);
}